// Round 2
// baseline (1008.722 us; speedup 1.0000x reference)
//
#include <hip/hip_runtime.h>

#define RR 48
#define GG 300
#define HW2 (GG * GG)
#define NPLANE (RR * HW2)
#define NVEC (RR * GG)
#define CC 27
#define NBUCK 32768  // 32^3 Morton buckets
#define TP 64        // points per block tile (37.4 KB LDS -> 4 blocks/CU)
#define TPP 65       // padded LDS column count

struct Axis { int i0, i1; float f; };

__device__ __forceinline__ Axis axis_interp(float x) {
  float g = x * 2.0f - 1.0f;
  float ih = (g + 1.0f) * 0.5f * (float)(GG - 1);
  int i0 = (int)floorf(ih);
  i0 = i0 < 0 ? 0 : (i0 > GG - 1 ? GG - 1 : i0);
  int i1 = i0 + 1 > GG - 1 ? GG - 1 : i0 + 1;
  Axis a; a.i0 = i0; a.i1 = i1; a.f = ih - (float)i0;
  return a;
}

// ---------------- sort machinery ----------------
__device__ __forceinline__ unsigned part3(unsigned v) {
  unsigned r = 0;
  r |= (v & 1u);
  r |= (v & 2u) << 2;
  r |= (v & 4u) << 4;
  r |= (v & 8u) << 6;
  r |= (v & 16u) << 8;
  return r;
}

__device__ __forceinline__ int morton_key(float x, float y, float z) {
  int qx = (int)(x * 32.0f); qx = qx < 0 ? 0 : (qx > 31 ? 31 : qx);
  int qy = (int)(y * 32.0f); qy = qy < 0 ? 0 : (qy > 31 ? 31 : qy);
  int qz = (int)(z * 32.0f); qz = qz < 0 ? 0 : (qz > 31 ? 31 : qz);
  return (int)(part3((unsigned)qx) | (part3((unsigned)qy) << 1) | (part3((unsigned)qz) << 2));
}

__global__ void __launch_bounds__(256) hist_kernel(const float* __restrict__ xyz, int n,
                                                   int* __restrict__ offs) {
  int i = blockIdx.x * blockDim.x + threadIdx.x;
  if (i >= n) return;
  atomicAdd(&offs[morton_key(xyz[i * 3], xyz[i * 3 + 1], xyz[i * 3 + 2])], 1);
}

__global__ void __launch_bounds__(1024) scan_kernel(int* __restrict__ offs) {
  __shared__ int part[1024];
  int t = threadIdx.x;
  int base = t * (NBUCK / 1024);
  int loc[NBUCK / 1024];
  int s = 0;
#pragma unroll
  for (int i = 0; i < NBUCK / 1024; ++i) { loc[i] = offs[base + i]; s += loc[i]; }
  part[t] = s;
  __syncthreads();
  for (int off = 1; off < 1024; off <<= 1) {
    int u = (t >= off) ? part[t - off] : 0;
    __syncthreads();
    part[t] += u;
    __syncthreads();
  }
  int excl = (t == 0) ? 0 : part[t - 1];
#pragma unroll
  for (int i = 0; i < NBUCK / 1024; ++i) {
    int c = loc[i];
    offs[base + i] = excl;
    excl += c;
  }
}

// Scatter: writes sorted (x,y,z,origIdx) records if sxyz is provided (16B,
// coalesced consumption later), else just the sorted index list.
__global__ void __launch_bounds__(256) scatter_kernel(const float* __restrict__ xyz, int n,
                                                      int* __restrict__ offs,
                                                      int* __restrict__ sidx,
                                                      float4* __restrict__ sxyz) {
  int i = blockIdx.x * blockDim.x + threadIdx.x;
  if (i >= n) return;
  float x = xyz[i * 3], y = xyz[i * 3 + 1], z = xyz[i * 3 + 2];
  int key = morton_key(x, y, z);
  int pos = atomicAdd(&offs[key], 1);
  if (sxyz) {
    sxyz[pos] = make_float4(x, y, z, __int_as_float(i));
  } else {
    sidx[pos] = i;
  }
}

// ---------------- layout transforms ----------------
// [R, HW2] -> [HW2, R], 3 planes via gridDim.y
__global__ void __launch_bounds__(256) transpose_planes(const float* __restrict__ p0,
                                                        const float* __restrict__ p1,
                                                        const float* __restrict__ p2,
                                                        float* __restrict__ t0,
                                                        float* __restrict__ t1,
                                                        float* __restrict__ t2) {
  __shared__ float tile[256 * 49];
  const float* in = (blockIdx.y == 0) ? p0 : (blockIdx.y == 1) ? p1 : p2;
  float* out = (blockIdx.y == 0) ? t0 : (blockIdx.y == 1) ? t1 : t2;
  int base = blockIdx.x * 256;
  int t = threadIdx.x;
  int pos = base + t;
#pragma unroll 1
  for (int r = 0; r < RR; ++r) {
    float v = (pos < HW2) ? in[r * HW2 + pos] : 0.f;
    tile[t * 49 + r] = v;
  }
  __syncthreads();
#pragma unroll 1
  for (int k = t; k < 256 * RR; k += 256) {
    int p = k / RR;
    int r = k - p * RR;
    int hw = base + p;
    if (hw < HW2) out[hw * RR + r] = tile[p * 49 + r];
  }
}

// [R, GG] -> [GG, R], all 3 vecs in one grid
__global__ void __launch_bounds__(256) transpose_vecs(const float* __restrict__ v0,
                                                      const float* __restrict__ v1,
                                                      const float* __restrict__ v2,
                                                      float* __restrict__ t0,
                                                      float* __restrict__ t1,
                                                      float* __restrict__ t2) {
  int e = blockIdx.x * blockDim.x + threadIdx.x;
  if (e >= 3 * NVEC) return;
  int v = e / NVEC;
  int rem = e - v * NVEC;
  int i = rem / RR;
  int r = rem - i * RR;
  const float* in = (v == 0) ? v0 : (v == 1) ? v1 : v2;
  float* out = (v == 0) ? t0 : (v == 1) ? t1 : t2;
  out[i * RR + r] = in[r * GG + i];
}

// ---------------- fused main ----------------
// One corner-run gather + interpolation for one seg; lane l<12 covers channels 4l..4l+3.
__device__ __forceinline__ void gather_seg(const float* __restrict__ P, Axis ai, Axis aj,
                                           const float* __restrict__ V, Axis ak,
                                           int r4, float* __restrict__ dst) {
  float fi = ai.f, fj = aj.f, fk = ak.f;
  float w00 = (1.f - fi) * (1.f - fj);
  float w01 = (1.f - fi) * fj;
  float w10 = fi * (1.f - fj);
  float w11 = fi * fj;
  float omk = 1.f - fk;
  float4 q00 = *(const float4*)(P + (ai.i0 * GG + aj.i0) * RR + r4);
  float4 q01 = *(const float4*)(P + (ai.i0 * GG + aj.i1) * RR + r4);
  float4 q10 = *(const float4*)(P + (ai.i1 * GG + aj.i0) * RR + r4);
  float4 q11 = *(const float4*)(P + (ai.i1 * GG + aj.i1) * RR + r4);
  float4 b0 = *(const float4*)(V + ak.i0 * RR + r4);
  float4 b1 = *(const float4*)(V + ak.i1 * RR + r4);
  float t0 = (w00 * q00.x + w01 * q01.x + w10 * q10.x + w11 * q11.x) * (omk * b0.x + fk * b1.x);
  float t1 = (w00 * q00.y + w01 * q01.y + w10 * q10.y + w11 * q11.y) * (omk * b0.y + fk * b1.y);
  float t2 = (w00 * q00.z + w01 * q01.z + w10 * q10.z + w11 * q11.z) * (omk * b0.z + fk * b1.z);
  float t3 = (w00 * q00.w + w01 * q01.w + w10 * q10.w + w11 * q11.w) * (omk * b0.w + fk * b1.w);
  dst[(r4 + 0) * TPP] = t0;
  dst[(r4 + 1) * TPP] = t1;
  dst[(r4 + 2) * TPP] = t2;
  dst[(r4 + 3) * TPP] = t3;
}

__global__ void __launch_bounds__(256, 4) tensorf_fused(
    const float4* __restrict__ sxyz, const int* __restrict__ sidx,
    const float* __restrict__ xyz,
    const float* __restrict__ Txy, const float* __restrict__ Txz, const float* __restrict__ Tyz,
    const float* __restrict__ Tx, const float* __restrict__ Ty, const float* __restrict__ Tz,
    const float* __restrict__ F, float* __restrict__ out, int n, int chunkLen) {
  __shared__ float featT[144 * TPP];  // 37.4 KB -> 4 blocks/CU
  __shared__ int oiS[TP];
  int b = blockIdx.x;
  int nb = (b & 7) * chunkLen + (b >> 3);  // XCD-aware: each XCD streams one Morton chunk
  int base = nb * TP;
  int tid = threadIdx.x;
  int g = tid >> 4;   // group 0..15, one point per group per iter
  int l = tid & 15;   // lane within group; lanes 0..11 do the loads

  // ---- phase 1: coalesced gather + interpolate -> featT[144][TP] ----
#pragma unroll 1
  for (int it = 0; it < TP / 16; ++it) {
    int pl = (it << 4) + g;
    int sp = base + pl;
    if (sp < n) {
      float x, y, z;
      int oi;
      if (sxyz) {
        float4 p4 = sxyz[sp];  // coalesced sorted records
        x = p4.x; y = p4.y; z = p4.z;
        oi = __float_as_int(p4.w);
      } else {
        oi = sidx[sp];
        x = xyz[oi * 3 + 0];
        y = xyz[oi * 3 + 1];
        z = xyz[oi * 3 + 2];
      }
      if (l == 12) oiS[pl] = oi;
      Axis ax = axis_interp(x), ay = axis_interp(y), az = axis_interp(z);
      if (l < 12) {
        int r4 = l << 2;
        float* dst = &featT[pl];
        gather_seg(Txy, ax, ay, Tz, az, r4, dst + 0 * RR * TPP);
        gather_seg(Txz, ax, az, Ty, ay, r4, dst + 1 * RR * TPP);
        gather_seg(Tyz, ay, az, Tx, ax, r4, dst + 2 * RR * TPP);
      }
    }
  }
  __syncthreads();

  // ---- phase 2: feat[144] @ F[144][27], 4 threads per point ----
  // q = wave index (uniform): q0 -> c0..6, q1 -> c7..13, q2 -> c14..20, q3 -> c20..26
  int p = tid & (TP - 1);
  int q = tid >> 6;  // wave-uniform
  int cbase = (q == 3) ? 20 : q * 7;
  const float* Fh = F + cbase;

  float acc[7];
#pragma unroll
  for (int c = 0; c < 7; ++c) acc[c] = 0.f;

#pragma unroll 4
  for (int k = 0; k < 144; ++k) {
    float fv = featT[k * TPP + p];
#pragma unroll
    for (int c = 0; c < 7; ++c) acc[c] = fmaf(fv, Fh[k * CC + c], acc[c]);
  }

  int sp = base + p;
  if (sp < n) {
    int oi = oiS[p];
    float* o = out + (size_t)oi * CC + cbase;
    if (q != 3) o[0] = acc[0];  // q3's c==0 (channel 20) is q2's copy
#pragma unroll
    for (int c = 1; c < 7; ++c) o[c] = acc[c];
  }
}

// ---------------- fallback (no workspace) ----------------
__global__ void __launch_bounds__(256) tensorf_naive(
    const float* __restrict__ xyz,
    const float* __restrict__ Pxy, const float* __restrict__ Pxz, const float* __restrict__ Pyz,
    const float* __restrict__ Vx, const float* __restrict__ Vy, const float* __restrict__ Vz,
    const float* __restrict__ F, float* __restrict__ out, int n) {
  int idx = blockIdx.x * blockDim.x + threadIdx.x;
  if (idx >= n) return;
  float x = xyz[idx * 3], y = xyz[idx * 3 + 1], z = xyz[idx * 3 + 2];
  Axis ax = axis_interp(x), ay = axis_interp(y), az = axis_interp(z);
  float acc[CC];
#pragma unroll
  for (int c = 0; c < CC; ++c) acc[c] = 0.f;
  const float* Ps[3] = {Pxy, Pxz, Pyz};
  const float* Vs[3] = {Vz, Vy, Vx};
  Axis A[3][2] = {{ax, ay}, {ax, az}, {ay, az}};
  Axis K[3] = {az, ay, ax};
#pragma unroll 1
  for (int s = 0; s < 3; ++s) {
    Axis ai = A[s][0], aj = A[s][1], ak = K[s];
    float fi = ai.f, fj = aj.f, fk = ak.f;
    float w00 = (1.f - fi) * (1.f - fj), w01 = (1.f - fi) * fj;
    float w10 = fi * (1.f - fj), w11 = fi * fj, omk = 1.f - fk;
#pragma unroll 1
    for (int r = 0; r < RR; ++r) {
      const float* pr = Ps[s] + r * HW2;
      float ft = (w00 * pr[ai.i0 * GG + aj.i0] + w01 * pr[ai.i0 * GG + aj.i1] +
                  w10 * pr[ai.i1 * GG + aj.i0] + w11 * pr[ai.i1 * GG + aj.i1]) *
                 (omk * Vs[s][r * GG + ak.i0] + fk * Vs[s][r * GG + ak.i1]);
      const float* Fr = F + (s * RR + r) * CC;
#pragma unroll
      for (int c = 0; c < CC; ++c) acc[c] = fmaf(ft, Fr[c], acc[c]);
    }
  }
  float* o = out + (size_t)idx * CC;
#pragma unroll
  for (int c = 0; c < CC; ++c) o[c] = acc[c];
}

extern "C" void kernel_launch(void* const* d_in, const int* in_sizes, int n_in,
                              void* d_out, int out_size, void* d_ws, size_t ws_size,
                              hipStream_t stream) {
  const float* xyz = (const float*)d_in[0];
  const float* pxy = (const float*)d_in[1];
  const float* pxz = (const float*)d_in[2];
  const float* pyz = (const float*)d_in[3];
  const float* vx = (const float*)d_in[4];
  const float* vy = (const float*)d_in[5];
  const float* vz = (const float*)d_in[6];
  const float* F = (const float*)d_in[7];
  float* out = (float*)d_out;
  int n = in_sizes[0] / 3;
  int nblk = (n + 255) / 256;

  size_t fixed = (size_t)(3 * NPLANE + 3 * NVEC) * sizeof(float) +
                 (size_t)NBUCK * sizeof(int);
  size_t need1 = fixed + (size_t)n * sizeof(int);      // sorted-index variant
  size_t need2 = fixed + (size_t)n * sizeof(float4);   // sorted-record variant

  if (ws_size >= need1) {
    float* w = (float*)d_ws;
    float* Txy = w;
    float* Txz = Txy + NPLANE;
    float* Tyz = Txz + NPLANE;
    float* Tx = Tyz + NPLANE;
    float* Ty = Tx + NVEC;
    float* Tz = Ty + NVEC;
    int* offs = (int*)(Tz + NVEC);

    int* sidx = nullptr;
    float4* sxyz = nullptr;
    if (ws_size >= need2) sxyz = (float4*)(offs + NBUCK);
    else sidx = (int*)(offs + NBUCK);

    int tb = (HW2 + 255) / 256;
    dim3 tg(tb, 3);
    transpose_planes<<<tg, 256, 0, stream>>>(pxy, pxz, pyz, Txy, Txz, Tyz);
    int vb = (3 * NVEC + 255) / 256;
    transpose_vecs<<<vb, 256, 0, stream>>>(vx, vy, vz, Tx, Ty, Tz);

    hipMemsetAsync(offs, 0, (size_t)NBUCK * sizeof(int), stream);
    hist_kernel<<<nblk, 256, 0, stream>>>(xyz, n, offs);
    scan_kernel<<<1, 1024, 0, stream>>>(offs);
    scatter_kernel<<<nblk, 256, 0, stream>>>(xyz, n, offs, sidx, sxyz);

    int ntile = (n + TP - 1) / TP;
    int chunkLen = (ntile + 7) / 8;
    tensorf_fused<<<chunkLen * 8, 256, 0, stream>>>(sxyz, sidx, xyz, Txy, Txz, Tyz,
                                                    Tx, Ty, Tz, F, out, n, chunkLen);
  } else {
    tensorf_naive<<<nblk, 256, 0, stream>>>(xyz, pxy, pxz, pyz, vx, vy, vz, F, out, n);
  }
}

// Round 3
// 598.934 us; speedup vs baseline: 1.6842x; 1.6842x over previous
//
#include <hip/hip_runtime.h>

#define RR 48
#define GG 300
#define HW2 (GG * GG)
#define NPLANE (RR * HW2)
#define NVEC (RR * GG)
#define CC 27
#define NBUCK 32768  // 32^3 Morton buckets
#define TP 64        // points per block tile (37.4 KB LDS -> 4 blocks/CU)
#define TPP 65       // padded LDS column count

struct Axis { int i0, i1; float f; };

__device__ __forceinline__ Axis axis_interp(float x) {
  float g = x * 2.0f - 1.0f;
  float ih = (g + 1.0f) * 0.5f * (float)(GG - 1);
  int i0 = (int)floorf(ih);
  i0 = i0 < 0 ? 0 : (i0 > GG - 1 ? GG - 1 : i0);
  int i1 = i0 + 1 > GG - 1 ? GG - 1 : i0 + 1;
  Axis a; a.i0 = i0; a.i1 = i1; a.f = ih - (float)i0;
  return a;
}

// ---------------- sort machinery ----------------
__device__ __forceinline__ unsigned part3(unsigned v) {
  unsigned r = 0;
  r |= (v & 1u);
  r |= (v & 2u) << 2;
  r |= (v & 4u) << 4;
  r |= (v & 8u) << 6;
  r |= (v & 16u) << 8;
  return r;
}

__device__ __forceinline__ int morton_key(float x, float y, float z) {
  int qx = (int)(x * 32.0f); qx = qx < 0 ? 0 : (qx > 31 ? 31 : qx);
  int qy = (int)(y * 32.0f); qy = qy < 0 ? 0 : (qy > 31 ? 31 : qy);
  int qz = (int)(z * 32.0f); qz = qz < 0 ? 0 : (qz > 31 ? 31 : qz);
  return (int)(part3((unsigned)qx) | (part3((unsigned)qy) << 1) | (part3((unsigned)qz) << 2));
}

__global__ void __launch_bounds__(256) hist_kernel(const float* __restrict__ xyz, int n,
                                                   int* __restrict__ offs) {
  int i = blockIdx.x * blockDim.x + threadIdx.x;
  if (i >= n) return;
  atomicAdd(&offs[morton_key(xyz[i * 3], xyz[i * 3 + 1], xyz[i * 3 + 2])], 1);
}

__global__ void __launch_bounds__(1024) scan_kernel(int* __restrict__ offs) {
  __shared__ int part[1024];
  int t = threadIdx.x;
  int base = t * (NBUCK / 1024);
  int loc[NBUCK / 1024];
  int s = 0;
#pragma unroll
  for (int i = 0; i < NBUCK / 1024; ++i) { loc[i] = offs[base + i]; s += loc[i]; }
  part[t] = s;
  __syncthreads();
  for (int off = 1; off < 1024; off <<= 1) {
    int u = (t >= off) ? part[t - off] : 0;
    __syncthreads();
    part[t] += u;
    __syncthreads();
  }
  int excl = (t == 0) ? 0 : part[t - 1];
#pragma unroll
  for (int i = 0; i < NBUCK / 1024; ++i) {
    int c = loc[i];
    offs[base + i] = excl;
    excl += c;
  }
}

// Scatter: writes sorted (x,y,z,origIdx) records if sxyz is provided (16B,
// coalesced consumption later), else just the sorted index list.
__global__ void __launch_bounds__(256) scatter_kernel(const float* __restrict__ xyz, int n,
                                                      int* __restrict__ offs,
                                                      int* __restrict__ sidx,
                                                      float4* __restrict__ sxyz) {
  int i = blockIdx.x * blockDim.x + threadIdx.x;
  if (i >= n) return;
  float x = xyz[i * 3], y = xyz[i * 3 + 1], z = xyz[i * 3 + 2];
  int key = morton_key(x, y, z);
  int pos = atomicAdd(&offs[key], 1);
  if (sxyz) {
    sxyz[pos] = make_float4(x, y, z, __int_as_float(i));
  } else {
    sidx[pos] = i;
  }
}

// ---------------- layout transforms ----------------
// [R, HW2] -> [HW2, R], 3 planes via gridDim.y
__global__ void __launch_bounds__(256) transpose_planes(const float* __restrict__ p0,
                                                        const float* __restrict__ p1,
                                                        const float* __restrict__ p2,
                                                        float* __restrict__ t0,
                                                        float* __restrict__ t1,
                                                        float* __restrict__ t2) {
  __shared__ float tile[256 * 49];
  const float* in = (blockIdx.y == 0) ? p0 : (blockIdx.y == 1) ? p1 : p2;
  float* out = (blockIdx.y == 0) ? t0 : (blockIdx.y == 1) ? t1 : t2;
  int base = blockIdx.x * 256;
  int t = threadIdx.x;
  int pos = base + t;
#pragma unroll 1
  for (int r = 0; r < RR; ++r) {
    float v = (pos < HW2) ? in[r * HW2 + pos] : 0.f;
    tile[t * 49 + r] = v;
  }
  __syncthreads();
#pragma unroll 1
  for (int k = t; k < 256 * RR; k += 256) {
    int p = k / RR;
    int r = k - p * RR;
    int hw = base + p;
    if (hw < HW2) out[hw * RR + r] = tile[p * 49 + r];
  }
}

// [R, GG] -> [GG, R], all 3 vecs in one grid
__global__ void __launch_bounds__(256) transpose_vecs(const float* __restrict__ v0,
                                                      const float* __restrict__ v1,
                                                      const float* __restrict__ v2,
                                                      float* __restrict__ t0,
                                                      float* __restrict__ t1,
                                                      float* __restrict__ t2) {
  int e = blockIdx.x * blockDim.x + threadIdx.x;
  if (e >= 3 * NVEC) return;
  int v = e / NVEC;
  int rem = e - v * NVEC;
  int i = rem / RR;
  int r = rem - i * RR;
  const float* in = (v == 0) ? v0 : (v == 1) ? v1 : v2;
  float* out = (v == 0) ? t0 : (v == 1) ? t1 : t2;
  out[i * RR + r] = in[r * GG + i];
}

// ---------------- fused main ----------------
// One corner-run gather + interpolation for one seg; lane l<12 covers channels 4l..4l+3.
__device__ __forceinline__ void gather_seg(const float* __restrict__ P, Axis ai, Axis aj,
                                           const float* __restrict__ V, Axis ak,
                                           int r4, float* __restrict__ dst) {
  float fi = ai.f, fj = aj.f, fk = ak.f;
  float w00 = (1.f - fi) * (1.f - fj);
  float w01 = (1.f - fi) * fj;
  float w10 = fi * (1.f - fj);
  float w11 = fi * fj;
  float omk = 1.f - fk;
  float4 q00 = *(const float4*)(P + (ai.i0 * GG + aj.i0) * RR + r4);
  float4 q01 = *(const float4*)(P + (ai.i0 * GG + aj.i1) * RR + r4);
  float4 q10 = *(const float4*)(P + (ai.i1 * GG + aj.i0) * RR + r4);
  float4 q11 = *(const float4*)(P + (ai.i1 * GG + aj.i1) * RR + r4);
  float4 b0 = *(const float4*)(V + ak.i0 * RR + r4);
  float4 b1 = *(const float4*)(V + ak.i1 * RR + r4);
  float t0 = (w00 * q00.x + w01 * q01.x + w10 * q10.x + w11 * q11.x) * (omk * b0.x + fk * b1.x);
  float t1 = (w00 * q00.y + w01 * q01.y + w10 * q10.y + w11 * q11.y) * (omk * b0.y + fk * b1.y);
  float t2 = (w00 * q00.z + w01 * q01.z + w10 * q10.z + w11 * q11.z) * (omk * b0.z + fk * b1.z);
  float t3 = (w00 * q00.w + w01 * q01.w + w10 * q10.w + w11 * q11.w) * (omk * b0.w + fk * b1.w);
  dst[(r4 + 0) * TPP] = t0;
  dst[(r4 + 1) * TPP] = t1;
  dst[(r4 + 2) * TPP] = t2;
  dst[(r4 + 3) * TPP] = t3;
}

__global__ void __launch_bounds__(256, 4) tensorf_fused(
    const float4* __restrict__ sxyz, const int* __restrict__ sidx,
    const float* __restrict__ xyz,
    const float* __restrict__ Txy, const float* __restrict__ Txz, const float* __restrict__ Tyz,
    const float* __restrict__ Tx, const float* __restrict__ Ty, const float* __restrict__ Tz,
    const float* __restrict__ F, float* __restrict__ out, int n, int chunkLen) {
  __shared__ float featT[144 * TPP];  // 37.4 KB -> 4 blocks/CU
  __shared__ int oiS[TP];
  int b = blockIdx.x;
  int nb = (b & 7) * chunkLen + (b >> 3);  // XCD-aware: each XCD streams one Morton chunk
  int base = nb * TP;
  int tid = threadIdx.x;
  int g = tid >> 4;   // group 0..15, one point per group per iter
  int l = tid & 15;   // lane within group; lanes 0..11 do the loads

  // ---- phase 1: coalesced gather + interpolate -> featT[144][TP] ----
#pragma unroll 1
  for (int it = 0; it < TP / 16; ++it) {
    int pl = (it << 4) + g;
    int sp = base + pl;
    if (sp < n) {
      float x, y, z;
      int oi;
      if (sxyz) {
        float4 p4 = sxyz[sp];  // coalesced sorted records
        x = p4.x; y = p4.y; z = p4.z;
        oi = __float_as_int(p4.w);
      } else {
        oi = sidx[sp];
        x = xyz[oi * 3 + 0];
        y = xyz[oi * 3 + 1];
        z = xyz[oi * 3 + 2];
      }
      if (l == 12) oiS[pl] = oi;
      Axis ax = axis_interp(x), ay = axis_interp(y), az = axis_interp(z);
      if (l < 12) {
        int r4 = l << 2;
        float* dst = &featT[pl];
        gather_seg(Txy, ax, ay, Tz, az, r4, dst + 0 * RR * TPP);
        gather_seg(Txz, ax, az, Ty, ay, r4, dst + 1 * RR * TPP);
        gather_seg(Tyz, ay, az, Tx, ax, r4, dst + 2 * RR * TPP);
      }
    }
  }
  __syncthreads();

  // ---- phase 2: feat[144] @ F[144][27], 4 threads per point ----
  // q = wave index, FORCED uniform via readfirstlane so the F pointer lives in
  // SGPRs and all F reads are s_load broadcasts (round-2 regression: plain
  // tid>>6 made these 1008 per-lane global_load_dword + VGPR address math).
  int p = tid & (TP - 1);
  int q = __builtin_amdgcn_readfirstlane(tid >> 6);  // wave-uniform 0..3
  int cbase = (q == 3) ? 20 : q * 7;  // q3 overlaps q2 at c20 to stay in-bounds
  const float* Fh = F + cbase;

  float acc[7];
#pragma unroll
  for (int c = 0; c < 7; ++c) acc[c] = 0.f;

#pragma unroll 4
  for (int k = 0; k < 144; ++k) {
    float fv = featT[k * TPP + p];
#pragma unroll
    for (int c = 0; c < 7; ++c) acc[c] = fmaf(fv, Fh[k * CC + c], acc[c]);
  }

  int sp = base + p;
  if (sp < n) {
    int oi = oiS[p];
    float* o = out + (size_t)oi * CC + cbase;
    if (q != 3) o[0] = acc[0];  // q3's c==0 (channel 20) is q2's copy
#pragma unroll
    for (int c = 1; c < 7; ++c) o[c] = acc[c];
  }
}

// ---------------- fallback (no workspace) ----------------
__global__ void __launch_bounds__(256) tensorf_naive(
    const float* __restrict__ xyz,
    const float* __restrict__ Pxy, const float* __restrict__ Pxz, const float* __restrict__ Pyz,
    const float* __restrict__ Vx, const float* __restrict__ Vy, const float* __restrict__ Vz,
    const float* __restrict__ F, float* __restrict__ out, int n) {
  int idx = blockIdx.x * blockDim.x + threadIdx.x;
  if (idx >= n) return;
  float x = xyz[idx * 3], y = xyz[idx * 3 + 1], z = xyz[idx * 3 + 2];
  Axis ax = axis_interp(x), ay = axis_interp(y), az = axis_interp(z);
  float acc[CC];
#pragma unroll
  for (int c = 0; c < CC; ++c) acc[c] = 0.f;
  const float* Ps[3] = {Pxy, Pxz, Pyz};
  const float* Vs[3] = {Vz, Vy, Vx};
  Axis A[3][2] = {{ax, ay}, {ax, az}, {ay, az}};
  Axis K[3] = {az, ay, ax};
#pragma unroll 1
  for (int s = 0; s < 3; ++s) {
    Axis ai = A[s][0], aj = A[s][1], ak = K[s];
    float fi = ai.f, fj = aj.f, fk = ak.f;
    float w00 = (1.f - fi) * (1.f - fj), w01 = (1.f - fi) * fj;
    float w10 = fi * (1.f - fj), w11 = fi * fj, omk = 1.f - fk;
#pragma unroll 1
    for (int r = 0; r < RR; ++r) {
      const float* pr = Ps[s] + r * HW2;
      float ft = (w00 * pr[ai.i0 * GG + aj.i0] + w01 * pr[ai.i0 * GG + aj.i1] +
                  w10 * pr[ai.i1 * GG + aj.i0] + w11 * pr[ai.i1 * GG + aj.i1]) *
                 (omk * Vs[s][r * GG + ak.i0] + fk * Vs[s][r * GG + ak.i1]);
      const float* Fr = F + (s * RR + r) * CC;
#pragma unroll
      for (int c = 0; c < CC; ++c) acc[c] = fmaf(ft, Fr[c], acc[c]);
    }
  }
  float* o = out + (size_t)idx * CC;
#pragma unroll
  for (int c = 0; c < CC; ++c) o[c] = acc[c];
}

extern "C" void kernel_launch(void* const* d_in, const int* in_sizes, int n_in,
                              void* d_out, int out_size, void* d_ws, size_t ws_size,
                              hipStream_t stream) {
  const float* xyz = (const float*)d_in[0];
  const float* pxy = (const float*)d_in[1];
  const float* pxz = (const float*)d_in[2];
  const float* pyz = (const float*)d_in[3];
  const float* vx = (const float*)d_in[4];
  const float* vy = (const float*)d_in[5];
  const float* vz = (const float*)d_in[6];
  const float* F = (const float*)d_in[7];
  float* out = (float*)d_out;
  int n = in_sizes[0] / 3;
  int nblk = (n + 255) / 256;

  size_t fixed = (size_t)(3 * NPLANE + 3 * NVEC) * sizeof(float) +
                 (size_t)NBUCK * sizeof(int);
  size_t need1 = fixed + (size_t)n * sizeof(int);      // sorted-index variant
  size_t need2 = fixed + (size_t)n * sizeof(float4);   // sorted-record variant

  if (ws_size >= need1) {
    float* w = (float*)d_ws;
    float* Txy = w;
    float* Txz = Txy + NPLANE;
    float* Tyz = Txz + NPLANE;
    float* Tx = Tyz + NPLANE;
    float* Ty = Tx + NVEC;
    float* Tz = Ty + NVEC;
    int* offs = (int*)(Tz + NVEC);

    int* sidx = nullptr;
    float4* sxyz = nullptr;
    if (ws_size >= need2) sxyz = (float4*)(offs + NBUCK);
    else sidx = (int*)(offs + NBUCK);

    int tb = (HW2 + 255) / 256;
    dim3 tg(tb, 3);
    transpose_planes<<<tg, 256, 0, stream>>>(pxy, pxz, pyz, Txy, Txz, Tyz);
    int vb = (3 * NVEC + 255) / 256;
    transpose_vecs<<<vb, 256, 0, stream>>>(vx, vy, vz, Tx, Ty, Tz);

    hipMemsetAsync(offs, 0, (size_t)NBUCK * sizeof(int), stream);
    hist_kernel<<<nblk, 256, 0, stream>>>(xyz, n, offs);
    scan_kernel<<<1, 1024, 0, stream>>>(offs);
    scatter_kernel<<<nblk, 256, 0, stream>>>(xyz, n, offs, sidx, sxyz);

    int ntile = (n + TP - 1) / TP;
    int chunkLen = (ntile + 7) / 8;
    tensorf_fused<<<chunkLen * 8, 256, 0, stream>>>(sxyz, sidx, xyz, Txy, Txz, Tyz,
                                                    Tx, Ty, Tz, F, out, n, chunkLen);
  } else {
    tensorf_naive<<<nblk, 256, 0, stream>>>(xyz, pxy, pxz, pyz, vx, vy, vz, F, out, n);
  }
}

// Round 4
// 538.711 us; speedup vs baseline: 1.8725x; 1.1118x over previous
//
#include <hip/hip_runtime.h>

#define RR 48
#define GG 300
#define HW2 (GG * GG)
#define NPLANE (RR * HW2)
#define NVEC (RR * GG)
#define CC 27
#define NBUCK 32768  // 32^3 Morton buckets
#define TP 64        // points per block tile (37.4 KB LDS -> 4 blocks/CU)
#define TPP 65       // padded LDS column count

#define PBLK ((HW2 + 255) / 256)      // 352 blocks per plane
#define PB3 (3 * PBLK)                // 1056 plane-transpose blocks
#define VBLK ((3 * NVEC + 255) / 256) // 169 vec-transpose blocks
#define TROW 260                      // LDS tile row stride (16B-aligned, bank-spread)

struct Axis { int i0, i1; float f; };

__device__ __forceinline__ Axis axis_interp(float x) {
  float g = x * 2.0f - 1.0f;
  float ih = (g + 1.0f) * 0.5f * (float)(GG - 1);
  int i0 = (int)floorf(ih);
  i0 = i0 < 0 ? 0 : (i0 > GG - 1 ? GG - 1 : i0);
  int i1 = i0 + 1 > GG - 1 ? GG - 1 : i0 + 1;
  Axis a; a.i0 = i0; a.i1 = i1; a.f = ih - (float)i0;
  return a;
}

// ---------------- sort machinery ----------------
__device__ __forceinline__ unsigned part3(unsigned v) {
  unsigned r = 0;
  r |= (v & 1u);
  r |= (v & 2u) << 2;
  r |= (v & 4u) << 4;
  r |= (v & 8u) << 6;
  r |= (v & 16u) << 8;
  return r;
}

__device__ __forceinline__ int morton_key(float x, float y, float z) {
  int qx = (int)(x * 32.0f); qx = qx < 0 ? 0 : (qx > 31 ? 31 : qx);
  int qy = (int)(y * 32.0f); qy = qy < 0 ? 0 : (qy > 31 ? 31 : qy);
  int qz = (int)(z * 32.0f); qz = qz < 0 ? 0 : (qz > 31 ? 31 : qz);
  return (int)(part3((unsigned)qx) | (part3((unsigned)qy) << 1) | (part3((unsigned)qz) << 2));
}

// ---------------- combined preprocessing: transposes + hist in one launch ---
// Blocks [0, PB3): plane transpose (float4 both sides via LDS [r][pos] tile)
// Blocks [PB3, PB3+VBLK): vec transpose
// Blocks [PB3+VBLK, ...): histogram (offs must be pre-zeroed)
__global__ void __launch_bounds__(256) preprocess_kernel(
    const float* __restrict__ p0, const float* __restrict__ p1, const float* __restrict__ p2,
    float* __restrict__ t0, float* __restrict__ t1, float* __restrict__ t2,
    const float* __restrict__ v0, const float* __restrict__ v1, const float* __restrict__ v2,
    float* __restrict__ tv0, float* __restrict__ tv1, float* __restrict__ tv2,
    const float* __restrict__ xyz, int n, int* __restrict__ offs) {
  __shared__ float tile[RR * TROW];  // 49.9 KB (only transpose blocks touch it)
  int bb = blockIdx.x;
  int t = threadIdx.x;

  if (bb < PB3) {
    // ---- plane transpose: [R][HW2] -> [HW2][R] ----
    int plane = bb / PBLK;
    int chunk = bb - plane * PBLK;
    const float* in = (plane == 0) ? p0 : (plane == 1) ? p1 : p2;
    float* outp = (plane == 0) ? t0 : (plane == 1) ? t1 : t2;
    int base = chunk * 256;
    if (base + 256 <= HW2) {
      // fast path: float4 in, b128 LDS, float4 out
      int p4 = t & 63;   // which float4 of the 256-wide position strip
      int rg = t >> 6;   // row group 0..3
#pragma unroll 1
      for (int i = 0; i < 12; ++i) {
        int r = i * 4 + rg;
        float4 v = *(const float4*)(in + (size_t)r * HW2 + base + p4 * 4);
        *(float4*)&tile[r * TROW + p4 * 4] = v;
      }
      __syncthreads();
#pragma unroll 1
      for (int jj = 0; jj < 12; ++jj) {
        int hw = ((jj & 3) << 6) + (t >> 2);        // 0..255
        int c4 = ((jj >> 2) << 2) + (t & 3);        // 0..11
        float4 w;
        w.x = tile[(c4 * 4 + 0) * TROW + hw];
        w.y = tile[(c4 * 4 + 1) * TROW + hw];
        w.z = tile[(c4 * 4 + 2) * TROW + hw];
        w.w = tile[(c4 * 4 + 3) * TROW + hw];
        *(float4*)(outp + (size_t)(base + hw) * RR + c4 * 4) = w;
      }
    } else {
      // tail block (one per plane): scalar with guards
      int pos = base + t;
#pragma unroll 1
      for (int r = 0; r < RR; ++r) {
        float v = (pos < HW2) ? in[(size_t)r * HW2 + pos] : 0.f;
        tile[r * TROW + t] = v;
      }
      __syncthreads();
#pragma unroll 1
      for (int k = t; k < 256 * RR; k += 256) {
        int p = k / RR;
        int r = k - p * RR;
        int hw = base + p;
        if (hw < HW2) outp[(size_t)hw * RR + r] = tile[r * TROW + p];
      }
    }
  } else if (bb < PB3 + VBLK) {
    // ---- vec transpose: [R][GG] -> [GG][R] ----
    int e = (bb - PB3) * 256 + t;
    if (e < 3 * NVEC) {
      int v = e / NVEC;
      int rem = e - v * NVEC;
      int i = rem / RR;
      int r = rem - i * RR;
      const float* in = (v == 0) ? v0 : (v == 1) ? v1 : v2;
      float* out = (v == 0) ? tv0 : (v == 1) ? tv1 : tv2;
      out[i * RR + r] = in[r * GG + i];
    }
  } else {
    // ---- histogram ----
    int i = (bb - PB3 - VBLK) * 256 + t;
    if (i < n) {
      atomicAdd(&offs[morton_key(xyz[i * 3], xyz[i * 3 + 1], xyz[i * 3 + 2])], 1);
    }
  }
}

__global__ void __launch_bounds__(1024) scan_kernel(int* __restrict__ offs) {
  __shared__ int part[1024];
  int t = threadIdx.x;
  int base = t * (NBUCK / 1024);
  int loc[NBUCK / 1024];
  int s = 0;
#pragma unroll
  for (int i = 0; i < NBUCK / 1024; ++i) { loc[i] = offs[base + i]; s += loc[i]; }
  part[t] = s;
  __syncthreads();
  for (int off = 1; off < 1024; off <<= 1) {
    int u = (t >= off) ? part[t - off] : 0;
    __syncthreads();
    part[t] += u;
    __syncthreads();
  }
  int excl = (t == 0) ? 0 : part[t - 1];
#pragma unroll
  for (int i = 0; i < NBUCK / 1024; ++i) {
    int c = loc[i];
    offs[base + i] = excl;
    excl += c;
  }
}

// Scatter: writes sorted (x,y,z,origIdx) records if sxyz is provided (16B,
// coalesced consumption later), else just the sorted index list.
__global__ void __launch_bounds__(256) scatter_kernel(const float* __restrict__ xyz, int n,
                                                      int* __restrict__ offs,
                                                      int* __restrict__ sidx,
                                                      float4* __restrict__ sxyz) {
  int i = blockIdx.x * blockDim.x + threadIdx.x;
  if (i >= n) return;
  float x = xyz[i * 3], y = xyz[i * 3 + 1], z = xyz[i * 3 + 2];
  int key = morton_key(x, y, z);
  int pos = atomicAdd(&offs[key], 1);
  if (sxyz) {
    sxyz[pos] = make_float4(x, y, z, __int_as_float(i));
  } else {
    sidx[pos] = i;
  }
}

// ---------------- fused main ----------------
// One corner-run gather + interpolation for one seg; lane l<12 covers channels 4l..4l+3.
__device__ __forceinline__ void gather_seg(const float* __restrict__ P, Axis ai, Axis aj,
                                           const float* __restrict__ V, Axis ak,
                                           int r4, float* __restrict__ dst) {
  float fi = ai.f, fj = aj.f, fk = ak.f;
  float w00 = (1.f - fi) * (1.f - fj);
  float w01 = (1.f - fi) * fj;
  float w10 = fi * (1.f - fj);
  float w11 = fi * fj;
  float omk = 1.f - fk;
  float4 q00 = *(const float4*)(P + (ai.i0 * GG + aj.i0) * RR + r4);
  float4 q01 = *(const float4*)(P + (ai.i0 * GG + aj.i1) * RR + r4);
  float4 q10 = *(const float4*)(P + (ai.i1 * GG + aj.i0) * RR + r4);
  float4 q11 = *(const float4*)(P + (ai.i1 * GG + aj.i1) * RR + r4);
  float4 b0 = *(const float4*)(V + ak.i0 * RR + r4);
  float4 b1 = *(const float4*)(V + ak.i1 * RR + r4);
  float t0 = (w00 * q00.x + w01 * q01.x + w10 * q10.x + w11 * q11.x) * (omk * b0.x + fk * b1.x);
  float t1 = (w00 * q00.y + w01 * q01.y + w10 * q10.y + w11 * q11.y) * (omk * b0.y + fk * b1.y);
  float t2 = (w00 * q00.z + w01 * q01.z + w10 * q10.z + w11 * q11.z) * (omk * b0.z + fk * b1.z);
  float t3 = (w00 * q00.w + w01 * q01.w + w10 * q10.w + w11 * q11.w) * (omk * b0.w + fk * b1.w);
  dst[(r4 + 0) * TPP] = t0;
  dst[(r4 + 1) * TPP] = t1;
  dst[(r4 + 2) * TPP] = t2;
  dst[(r4 + 3) * TPP] = t3;
}

__global__ void __launch_bounds__(256, 4) tensorf_fused(
    const float4* __restrict__ sxyz, const int* __restrict__ sidx,
    const float* __restrict__ xyz,
    const float* __restrict__ Txy, const float* __restrict__ Txz, const float* __restrict__ Tyz,
    const float* __restrict__ Tx, const float* __restrict__ Ty, const float* __restrict__ Tz,
    const float* __restrict__ F, float* __restrict__ out, int n, int chunkLen) {
  __shared__ float featT[144 * TPP];  // 37.4 KB -> 4 blocks/CU
  __shared__ int oiS[TP];
  int b = blockIdx.x;
  int nb = (b & 7) * chunkLen + (b >> 3);  // XCD-aware: each XCD streams one Morton chunk
  int base = nb * TP;
  int tid = threadIdx.x;
  int g = tid >> 4;   // group 0..15, one point per group per iter
  int l = tid & 15;   // lane within group; lanes 0..11 do the loads

  // ---- phase 1: coalesced gather + interpolate -> featT[144][TP] ----
#pragma unroll 1
  for (int it = 0; it < TP / 16; ++it) {
    int pl = (it << 4) + g;
    int sp = base + pl;
    if (sp < n) {
      float x, y, z;
      int oi;
      if (sxyz) {
        float4 p4 = sxyz[sp];  // coalesced sorted records
        x = p4.x; y = p4.y; z = p4.z;
        oi = __float_as_int(p4.w);
      } else {
        oi = sidx[sp];
        x = xyz[oi * 3 + 0];
        y = xyz[oi * 3 + 1];
        z = xyz[oi * 3 + 2];
      }
      if (l == 12) oiS[pl] = oi;
      Axis ax = axis_interp(x), ay = axis_interp(y), az = axis_interp(z);
      if (l < 12) {
        int r4 = l << 2;
        float* dst = &featT[pl];
        gather_seg(Txy, ax, ay, Tz, az, r4, dst + 0 * RR * TPP);
        gather_seg(Txz, ax, az, Ty, ay, r4, dst + 1 * RR * TPP);
        gather_seg(Tyz, ay, az, Tx, ax, r4, dst + 2 * RR * TPP);
      }
    }
  }
  __syncthreads();

  // ---- phase 2: feat[144] @ F[144][27], 4 threads per point ----
  // q = wave index, FORCED uniform via readfirstlane so the F pointer lives in
  // SGPRs and all F reads are s_load broadcasts (round-2 regression: plain
  // tid>>6 made these 1008 per-lane global_load_dword + VGPR address math).
  int p = tid & (TP - 1);
  int q = __builtin_amdgcn_readfirstlane(tid >> 6);  // wave-uniform 0..3
  int cbase = (q == 3) ? 20 : q * 7;  // q3 overlaps q2 at c20 to stay in-bounds
  const float* Fh = F + cbase;

  float acc[7];
#pragma unroll
  for (int c = 0; c < 7; ++c) acc[c] = 0.f;

#pragma unroll 4
  for (int k = 0; k < 144; ++k) {
    float fv = featT[k * TPP + p];
#pragma unroll
    for (int c = 0; c < 7; ++c) acc[c] = fmaf(fv, Fh[k * CC + c], acc[c]);
  }

  int sp = base + p;
  if (sp < n) {
    int oi = oiS[p];
    float* o = out + (size_t)oi * CC + cbase;
    if (q != 3) o[0] = acc[0];  // q3's c==0 (channel 20) is q2's copy
#pragma unroll
    for (int c = 1; c < 7; ++c) o[c] = acc[c];
  }
}

// ---------------- fallback (no workspace) ----------------
__global__ void __launch_bounds__(256) tensorf_naive(
    const float* __restrict__ xyz,
    const float* __restrict__ Pxy, const float* __restrict__ Pxz, const float* __restrict__ Pyz,
    const float* __restrict__ Vx, const float* __restrict__ Vy, const float* __restrict__ Vz,
    const float* __restrict__ F, float* __restrict__ out, int n) {
  int idx = blockIdx.x * blockDim.x + threadIdx.x;
  if (idx >= n) return;
  float x = xyz[idx * 3], y = xyz[idx * 3 + 1], z = xyz[idx * 3 + 2];
  Axis ax = axis_interp(x), ay = axis_interp(y), az = axis_interp(z);
  float acc[CC];
#pragma unroll
  for (int c = 0; c < CC; ++c) acc[c] = 0.f;
  const float* Ps[3] = {Pxy, Pxz, Pyz};
  const float* Vs[3] = {Vz, Vy, Vx};
  Axis A[3][2] = {{ax, ay}, {ax, az}, {ay, az}};
  Axis K[3] = {az, ay, ax};
#pragma unroll 1
  for (int s = 0; s < 3; ++s) {
    Axis ai = A[s][0], aj = A[s][1], ak = K[s];
    float fi = ai.f, fj = aj.f, fk = ak.f;
    float w00 = (1.f - fi) * (1.f - fj), w01 = (1.f - fi) * fj;
    float w10 = fi * (1.f - fj), w11 = fi * fj, omk = 1.f - fk;
#pragma unroll 1
    for (int r = 0; r < RR; ++r) {
      const float* pr = Ps[s] + r * HW2;
      float ft = (w00 * pr[ai.i0 * GG + aj.i0] + w01 * pr[ai.i0 * GG + aj.i1] +
                  w10 * pr[ai.i1 * GG + aj.i0] + w11 * pr[ai.i1 * GG + aj.i1]) *
                 (omk * Vs[s][r * GG + ak.i0] + fk * Vs[s][r * GG + ak.i1]);
      const float* Fr = F + (s * RR + r) * CC;
#pragma unroll
      for (int c = 0; c < CC; ++c) acc[c] = fmaf(ft, Fr[c], acc[c]);
    }
  }
  float* o = out + (size_t)idx * CC;
#pragma unroll
  for (int c = 0; c < CC; ++c) o[c] = acc[c];
}

extern "C" void kernel_launch(void* const* d_in, const int* in_sizes, int n_in,
                              void* d_out, int out_size, void* d_ws, size_t ws_size,
                              hipStream_t stream) {
  const float* xyz = (const float*)d_in[0];
  const float* pxy = (const float*)d_in[1];
  const float* pxz = (const float*)d_in[2];
  const float* pyz = (const float*)d_in[3];
  const float* vx = (const float*)d_in[4];
  const float* vy = (const float*)d_in[5];
  const float* vz = (const float*)d_in[6];
  const float* F = (const float*)d_in[7];
  float* out = (float*)d_out;
  int n = in_sizes[0] / 3;
  int nblk = (n + 255) / 256;

  size_t fixed = (size_t)(3 * NPLANE + 3 * NVEC) * sizeof(float) +
                 (size_t)NBUCK * sizeof(int);
  size_t need1 = fixed + (size_t)n * sizeof(int);      // sorted-index variant
  size_t need2 = fixed + (size_t)n * sizeof(float4);   // sorted-record variant

  if (ws_size >= need1) {
    float* w = (float*)d_ws;
    float* Txy = w;
    float* Txz = Txy + NPLANE;
    float* Tyz = Txz + NPLANE;
    float* Tx = Tyz + NPLANE;
    float* Ty = Tx + NVEC;
    float* Tz = Ty + NVEC;
    int* offs = (int*)(Tz + NVEC);

    int* sidx = nullptr;
    float4* sxyz = nullptr;
    if (ws_size >= need2) sxyz = (float4*)(offs + NBUCK);
    else sidx = (int*)(offs + NBUCK);

    hipMemsetAsync(offs, 0, (size_t)NBUCK * sizeof(int), stream);
    // one launch: plane transposes + vec transposes + histogram (independent)
    preprocess_kernel<<<PB3 + VBLK + nblk, 256, 0, stream>>>(
        pxy, pxz, pyz, Txy, Txz, Tyz, vx, vy, vz, Tx, Ty, Tz, xyz, n, offs);
    scan_kernel<<<1, 1024, 0, stream>>>(offs);
    scatter_kernel<<<nblk, 256, 0, stream>>>(xyz, n, offs, sidx, sxyz);

    int ntile = (n + TP - 1) / TP;
    int chunkLen = (ntile + 7) / 8;
    tensorf_fused<<<chunkLen * 8, 256, 0, stream>>>(sxyz, sidx, xyz, Txy, Txz, Tyz,
                                                    Tx, Ty, Tz, F, out, n, chunkLen);
  } else {
    tensorf_naive<<<nblk, 256, 0, stream>>>(xyz, pxy, pxz, pyz, vx, vy, vz, F, out, n);
  }
}